// Round 8
// baseline (74.867 us; speedup 1.0000x reference)
//
#include <hip/hip_runtime.h>
#include <cfloat>
#include <cmath>

#define NB     4
#define NPTS   4096
#define NLAT   512
#define RPTS   16                 // i-points per thread
#define CJ     64                 // j-points per block
#define NJC    (NPTS / CJ)        // 64 j-chunks
#define NBLK   (3 * NB * NJC)     // 768 logical blocks
#define DUP    2                  // PROBE: run A's work twice -> visible in rocprof

// ---------------------------------------------------------------------------
// Prep: transform both point sets to (-2x, -2y, -2z, |p|^2) float4.
// grid = NB*NPTS/256 = 64 blocks.
// ---------------------------------------------------------------------------
__global__ __launch_bounds__(256) void k_prep(
    const float* __restrict__ pred_pos, const float* __restrict__ targ_pos,
    float4* __restrict__ predT, float4* __restrict__ targT)
{
    const int i = blockIdx.x * 256 + threadIdx.x;
    {
        const float x = pred_pos[3*i], y = pred_pos[3*i+1], z = pred_pos[3*i+2];
        predT[i] = make_float4(-2.f*x, -2.f*y, -2.f*z, fmaf(z,z,fmaf(y,y,x*x)));
    }
    {
        const float x = targ_pos[3*i], y = targ_pos[3*i+1], z = targ_pos[3*i+2];
        targT[i] = make_float4(-2.f*x, -2.f*y, -2.f*z, fmaf(z,z,fmaf(y,y,x*x)));
    }
}

// ---------------------------------------------------------------------------
// Kernel A (R4 structure, PROBE grid x2): partial nearest-distance mins.
// grid = DUP*768; blocks >= 768 redo identical work (identical stores ->
// deterministic). Scalar j-loads (block-uniform ob4[j]), 16 i-points/thread,
// per j-pair-chain 6 fma + 1 min3.
// ---------------------------------------------------------------------------
__global__ __launch_bounds__(256) void k_min_dist(
    const float* __restrict__ pred_pos,
    const float* __restrict__ targ_pos,
    const float4* __restrict__ predT,
    const float4* __restrict__ targT,
    float* __restrict__ part_mins /* [3][NB][NJC][NPTS] */)
{
    int fb = blockIdx.x;
    if (fb >= NBLK) fb -= NBLK;        // probe duplicate -> same work

    const int tid  = threadIdx.x;
    const int jc   = fb & (NJC - 1);
    const int b    = (fb >> 6) & 3;
    const int mode = fb >> 8;

    const float*  pb  = ((mode == 1) ? targ_pos : pred_pos) + (size_t)b * NPTS * 3;
    const float4* ob4 = ((mode == 0) ? targT : predT) + (size_t)b * NPTS + jc * CJ;

    float px[RPTS], py[RPTS], pz[RPTS], acc[RPTS];
    #pragma unroll
    for (int k = 0; k < RPTS; ++k) {
        const int i = tid + (k << 8);
        px[k] = pb[3*i]; py[k] = pb[3*i+1]; pz[k] = pb[3*i+2];
        acc[k] = FLT_MAX;
    }

    if (mode != 2) {
        #pragma unroll 2
        for (int j = 0; j < CJ; j += 2) {
            const float4 o1 = ob4[j];
            const float4 o2 = ob4[j + 1];
            #pragma unroll
            for (int k = 0; k < RPTS; ++k) {
                float t1 = fmaf(o1.x, px[k], o1.w);
                t1 = fmaf(o1.y, py[k], t1);
                t1 = fmaf(o1.z, pz[k], t1);
                float t2 = fmaf(o2.x, px[k], o2.w);
                t2 = fmaf(o2.y, py[k], t2);
                t2 = fmaf(o2.z, pz[k], t2);
                acc[k] = fminf(acc[k], fminf(t1, t2));   // -> v_min3_f32
            }
        }
    } else {
        const int  kself = jc >> 2;                // block-uniform
        const bool aff   = (tid >> 6) == (jc & 3);
        const int  jself = tid & 63;               // valid when aff
        float sx = 0.f, sy = 0.f, sz = 0.f;
        #pragma unroll
        for (int k = 0; k < RPTS; ++k) {
            sx = (k == kself) ? px[k] : sx;
            sy = (k == kself) ? py[k] : sy;
            sz = (k == kself) ? pz[k] : sz;
        }
        float accf = FLT_MAX;
        #pragma unroll 2
        for (int j = 0; j < CJ; j += 2) {
            const float4 o1 = ob4[j];
            const float4 o2 = ob4[j + 1];
            #pragma unroll
            for (int k = 0; k < RPTS; ++k) {
                float t1 = fmaf(o1.x, px[k], o1.w);
                t1 = fmaf(o1.y, py[k], t1);
                t1 = fmaf(o1.z, pz[k], t1);
                float t2 = fmaf(o2.x, px[k], o2.w);
                t2 = fmaf(o2.y, py[k], t2);
                t2 = fmaf(o2.z, pz[k], t2);
                acc[k] = fminf(acc[k], fminf(t1, t2));
            }
            float f1 = fmaf(o1.x, sx, o1.w);
            f1 = fmaf(o1.y, sy, f1);
            f1 = fmaf(o1.z, sz, f1);
            f1 = (j == jself) ? FLT_MAX : f1;
            float f2 = fmaf(o2.x, sx, o2.w);
            f2 = fmaf(o2.y, sy, f2);
            f2 = fmaf(o2.z, sz, f2);
            f2 = ((j + 1) == jself) ? FLT_MAX : f2;
            accf = fminf(accf, fminf(f1, f2));
        }
        #pragma unroll
        for (int k = 0; k < RPTS; ++k)
            acc[k] = (aff && k == kself) ? accf : acc[k];
    }

    float* mbase = part_mins + (((size_t)mode * NB + b) * NJC + jc) * NPTS;
    #pragma unroll
    for (int k = 0; k < RPTS; ++k) {
        const float p2 = fmaf(pz[k], pz[k], fmaf(py[k], py[k], px[k]*px[k]));
        mbase[tid + (k << 8)] = acc[k] + p2;    // coalesced per k
    }
}

// ---------------------------------------------------------------------------
__device__ __forceinline__ float block_sum(float v, float* red)
{
    #pragma unroll
    for (int o = 32; o >= 1; o >>= 1) v += __shfl_xor(v, o);
    const int w = threadIdx.x >> 6;
    __syncthreads();
    if ((threadIdx.x & 63) == 0) red[w] = v;
    __syncthreads();
    return red[0] + red[1] + red[2] + red[3];
}

// ---------------------------------------------------------------------------
// Fold: grid = 3*NB*16 = 192 blocks; block 256. Thread t owns one i-point,
// folds NJC partials (coalesced, stride NPTS), block-reduces sum & sumsq.
// ---------------------------------------------------------------------------
__global__ __launch_bounds__(256) void k_fold(
    const float* __restrict__ part_mins,
    float* __restrict__ sums /* [192] */, float* __restrict__ sumsqs /* [192] */)
{
    __shared__ float red[4];
    const int blk   = blockIdx.x;
    const int slice = blk & 15;
    const int b     = (blk >> 4) & 3;
    const int mode  = blk >> 6;
    const float* base = part_mins + ((size_t)mode * NB + b) * NJC * NPTS
                        + slice * 256 + threadIdx.x;
    float m = FLT_MAX;
    #pragma unroll 8
    for (int jc = 0; jc < NJC; ++jc)
        m = fminf(m, base[(size_t)jc * NPTS]);
    const float s  = block_sum(m, red);
    const float s2 = block_sum(m * m, red);
    if (threadIdx.x == 0) { sums[blk] = s; sumsqs[blk] = s2; }
}

// ---------------------------------------------------------------------------
// Finalize: KL + sizing MSE + combine. grid = 1, block = 256.
// ---------------------------------------------------------------------------
__global__ __launch_bounds__(256) void k_finalize(
    const float* __restrict__ pred_sizing,
    const float* __restrict__ targ_sizing,
    const float* __restrict__ mu,
    const float* __restrict__ logvar,
    const float* __restrict__ sums,
    const float* __restrict__ sumsqs,
    float* __restrict__ out)
{
    __shared__ float red[4];
    const int tid = threadIdx.x;

    float kls = 0.f;
    for (int i = tid; i < NB * NLAT; i += 256) {
        const float lv = logvar[i], m = mu[i];
        kls += 1.f + lv - m * m - expf(lv);
    }
    float szs = 0.f;
    #pragma unroll 4
    for (int i = tid; i < NB * NPTS; i += 256) {
        const float d = pred_sizing[i] - targ_sizing[i];
        szs += d * d;
    }
    kls = block_sum(kls, red);
    szs = block_sum(szs, red);

    if (tid == 0) {
        float cd_sum = 0.f, dens_sum = 0.f;
        for (int b = 0; b < NB; ++b) {
            float s01 = 0.f, sS = 0.f, sS2 = 0.f;
            for (int s = 0; s < 16; ++s) {
                s01 += sums[b * 16 + s] + sums[64 + b * 16 + s];
                sS  += sums[128 + b * 16 + s];
                sS2 += sumsqs[128 + b * 16 + s];
            }
            cd_sum += s01 / (float)NPTS;
            const float var = (sS2 - sS * sS / (float)NPTS) / (float)(NPTS - 1);
            dens_sum += sqrtf(fmaxf(var, 0.f));
        }
        const float cd     = cd_sum / (float)NB;
        const float dens   = dens_sum / (float)NB;
        const float kl     = -0.5f * kls / (float)(NB * NLAT);
        const float sizing = szs / (float)(NB * NPTS);
        out[0] = cd + 0.001f * kl + 0.1f * dens + 0.05f * sizing;
    }
}

// ---------------------------------------------------------------------------
extern "C" void kernel_launch(void* const* d_in, const int* in_sizes, int n_in,
                              void* d_out, int out_size, void* d_ws, size_t ws_size,
                              hipStream_t stream)
{
    const float* pred_pos    = (const float*)d_in[0];
    const float* pred_sizing = (const float*)d_in[1];
    const float* targ_pos    = (const float*)d_in[2];
    const float* targ_sizing = (const float*)d_in[3];
    const float* mu          = (const float*)d_in[4];
    const float* logvar      = (const float*)d_in[5];

    float4* predT = (float4*)d_ws;                               // 256 KiB
    float4* targT = predT + (size_t)NB * NPTS;                   // 256 KiB
    float*  part_mins = (float*)(targT + (size_t)NB * NPTS);     // 12.6 MiB
    float*  sums   = part_mins + (size_t)3 * NB * NJC * NPTS;    // 192
    float*  sumsqs = sums + 192;                                 // 192

    k_prep<<<dim3(NB * NPTS / 256), dim3(256), 0, stream>>>(
        pred_pos, targ_pos, predT, targT);
    // PROBE: grid x2 -> one dispatch big enough to surface in rocprof top-5.
    k_min_dist<<<dim3(DUP * NBLK), dim3(256), 0, stream>>>(
        pred_pos, targ_pos, predT, targT, part_mins);
    k_fold<<<dim3(192), dim3(256), 0, stream>>>(part_mins, sums, sumsqs);
    k_finalize<<<dim3(1), dim3(256), 0, stream>>>(
        pred_sizing, targ_sizing, mu, logvar, sums, sumsqs, (float*)d_out);
}

// Round 9
// 47.710 us; speedup vs baseline: 1.5692x; 1.5692x over previous
//
#include <hip/hip_runtime.h>
#include <cfloat>
#include <cmath>

#define NB     4
#define NPTS   4096
#define NLAT   512
#define RPTS   16                 // i-points per thread (16*256 = all 4096)
#define CJ     32                 // j-points per block
#define NJC    (NPTS / CJ)        // 128 j-chunks
#define NBLK   (3 * NB * NJC)     // 1536 blocks

// ---------------------------------------------------------------------------
// Kernel A: nearest-distance mins with global uint-atomicMin combine.
//   mode 0: pred -> target   mode 1: target -> pred   mode 2: pred self
// grid = 1536, block = 256, __launch_bounds__(256,4) -> <=128 VGPR: the
// ~80-float live set (px/py/pz/acc x16 + j temps) fits WITHOUT AGPR spills
// (R8 probe: default heuristic allocated 48 VGPR -> spill traffic ~doubled
// VALU ops). LDS stages 32 transformed j-points (in-kernel transform:
// o' = (-2ox,-2oy,-2oz,|o|^2)); per j-pair-chain 6 fma + 1 min3.
// Epilogue: d = max(acc + |p|^2, 0) >= 0  ->  uint bit order == float order
// -> atomicMin(uint) is deterministic (min is order-independent).
// Mode-2 self-pair: only threads tid>>5 == jc&7 at chain kself = jc>>3,
// j = tid&31 -> one extra block-uniform fix chain, no per-pair compares.
// ---------------------------------------------------------------------------
__global__ __launch_bounds__(256, 4) void k_min_dist(
    const float* __restrict__ pred_pos,
    const float* __restrict__ targ_pos,
    unsigned int* __restrict__ mins /* [3][NB][NPTS], pre-set 0xFFFFFFFF */)
{
    __shared__ float4 lds[CJ];    // 512 B

    const int tid  = threadIdx.x;
    const int jc   = blockIdx.x & (NJC - 1);
    const int b    = (blockIdx.x >> 7) & 3;
    const int mode = blockIdx.x >> 9;

    const float* pts = (mode == 1) ? targ_pos : pred_pos;
    const float* oth = (mode == 0) ? targ_pos : pred_pos;

    // stage + transform the j-chunk
    if (tid < CJ) {
        const float* ob = oth + ((size_t)b * NPTS + jc * CJ) * 3;
        const float x = ob[3 * tid], y = ob[3 * tid + 1], z = ob[3 * tid + 2];
        const float o2 = fmaf(z, z, fmaf(y, y, x * x));
        lds[tid] = make_float4(-2.f * x, -2.f * y, -2.f * z, o2);
    }

    // this thread's 16 i-points (raw)
    const float* pb = pts + (size_t)b * NPTS * 3;
    float px[RPTS], py[RPTS], pz[RPTS], acc[RPTS];
    #pragma unroll
    for (int k = 0; k < RPTS; ++k) {
        const float* pp = pb + 3 * (tid + (k << 8));
        px[k] = pp[0]; py[k] = pp[1]; pz[k] = pp[2];
        acc[k] = FLT_MAX;
    }
    __syncthreads();

    if (mode != 2) {
        #pragma unroll 2
        for (int j = 0; j < CJ; j += 2) {
            const float4 o1 = lds[j];
            const float4 o2 = lds[j + 1];
            #pragma unroll
            for (int k = 0; k < RPTS; ++k) {
                float t1 = fmaf(o1.x, px[k], o1.w);
                t1 = fmaf(o1.y, py[k], t1);
                t1 = fmaf(o1.z, pz[k], t1);
                float t2 = fmaf(o2.x, px[k], o2.w);
                t2 = fmaf(o2.y, py[k], t2);
                t2 = fmaf(o2.z, pz[k], t2);
                acc[k] = fminf(acc[k], fminf(t1, t2));   // -> v_min3_f32
            }
        }
    } else {
        const bool aff   = (tid >> 5) == (jc & 7);
        const int  kself = jc >> 3;                // block-uniform
        const int  jself = tid & 31;               // valid when aff
        float sx = px[0], sy = py[0], sz = pz[0];
        #pragma unroll
        for (int k = 1; k < RPTS; ++k) {
            sx = (k == kself) ? px[k] : sx;
            sy = (k == kself) ? py[k] : sy;
            sz = (k == kself) ? pz[k] : sz;
        }
        float accf = FLT_MAX;
        #pragma unroll 2
        for (int j = 0; j < CJ; j += 2) {
            const float4 o1 = lds[j];
            const float4 o2 = lds[j + 1];
            #pragma unroll
            for (int k = 0; k < RPTS; ++k) {
                float t1 = fmaf(o1.x, px[k], o1.w);
                t1 = fmaf(o1.y, py[k], t1);
                t1 = fmaf(o1.z, pz[k], t1);
                float t2 = fmaf(o2.x, px[k], o2.w);
                t2 = fmaf(o2.y, py[k], t2);
                t2 = fmaf(o2.z, pz[k], t2);
                acc[k] = fminf(acc[k], fminf(t1, t2));
            }
            float f1 = fmaf(o1.x, sx, o1.w);
            f1 = fmaf(o1.y, sy, f1);
            f1 = fmaf(o1.z, sz, f1);
            f1 = (j == jself) ? FLT_MAX : f1;
            float f2 = fmaf(o2.x, sx, o2.w);
            f2 = fmaf(o2.y, sy, f2);
            f2 = fmaf(o2.z, sz, f2);
            f2 = ((j + 1) == jself) ? FLT_MAX : f2;
            accf = fminf(accf, fminf(f1, f2));
        }
        #pragma unroll
        for (int k = 0; k < RPTS; ++k)
            acc[k] = (aff && k == kself) ? accf : acc[k];
    }

    unsigned int* mb = mins + ((size_t)mode * NB + b) * NPTS;
    #pragma unroll
    for (int k = 0; k < RPTS; ++k) {
        const float p2 = fmaf(pz[k], pz[k], fmaf(py[k], py[k], px[k] * px[k]));
        const float v  = fmaxf(acc[k] + p2, 0.f);        // >=0: uint==float order
        atomicMin(&mb[tid + (k << 8)], __float_as_uint(v));
    }
}

// ---------------------------------------------------------------------------
__device__ __forceinline__ float block_sum(float v, float* red)
{
    #pragma unroll
    for (int o = 32; o >= 1; o >>= 1) v += __shfl_xor(v, o);
    const int w = threadIdx.x >> 6;
    __syncthreads();
    if ((threadIdx.x & 63) == 0) red[w] = v;
    __syncthreads();
    return red[0] + red[1] + red[2] + red[3];
}

// ---------------------------------------------------------------------------
// Finalize (everything small): grid = 1, block = 256. Reads the 192 KiB mins
// (float bit patterns), per-batch Chamfer sums + self sum/sumsq, plus KL and
// sizing MSE; combines to the scalar loss. All fixed-order -> deterministic.
// ---------------------------------------------------------------------------
__global__ __launch_bounds__(256) void k_final(
    const unsigned int* __restrict__ mins,
    const float* __restrict__ pred_sizing,
    const float* __restrict__ targ_sizing,
    const float* __restrict__ mu,
    const float* __restrict__ logvar,
    float* __restrict__ out)
{
    __shared__ float red[4];
    __shared__ float acc2[2];
    const int tid = threadIdx.x;

    float cd_acc = 0.f, dens_acc = 0.f;          // used by tid 0 only
    for (int b = 0; b < NB; ++b) {
        const uint4* p0 = (const uint4*)(mins + (size_t)0 * NB * NPTS + b * NPTS);
        const uint4* p1 = (const uint4*)(mins + (size_t)1 * NB * NPTS + b * NPTS);
        const uint4* p2 = (const uint4*)(mins + (size_t)2 * NB * NPTS + b * NPTS);
        float s1 = 0.f, s3 = 0.f, q3 = 0.f;
        for (int i = tid; i < NPTS / 4; i += 256) {
            const uint4 a = p0[i], c = p1[i], d = p2[i];
            s1 += __uint_as_float(a.x) + __uint_as_float(a.y)
                + __uint_as_float(a.z) + __uint_as_float(a.w)
                + __uint_as_float(c.x) + __uint_as_float(c.y)
                + __uint_as_float(c.z) + __uint_as_float(c.w);
            const float f0 = __uint_as_float(d.x), f1 = __uint_as_float(d.y);
            const float f2 = __uint_as_float(d.z), f3 = __uint_as_float(d.w);
            s3 += f0 + f1 + f2 + f3;
            q3 += fmaf(f0, f0, fmaf(f1, f1, fmaf(f2, f2, f3 * f3)));
        }
        s1 = block_sum(s1, red);
        s3 = block_sum(s3, red);
        q3 = block_sum(q3, red);
        if (tid == 0) {
            cd_acc += s1 / (float)NPTS;
            const float var = (q3 - s3 * s3 / (float)NPTS) / (float)(NPTS - 1);
            dens_acc += sqrtf(fmaxf(var, 0.f));
        }
    }
    if (tid == 0) { acc2[0] = cd_acc; acc2[1] = dens_acc; }

    float kls = 0.f;
    for (int i = tid; i < NB * NLAT; i += 256) {
        const float lv = logvar[i], m = mu[i];
        kls += 1.f + lv - m * m - expf(lv);
    }
    kls = block_sum(kls, red);

    const float4* ps = (const float4*)pred_sizing;
    const float4* ts = (const float4*)targ_sizing;
    float szs = 0.f;
    for (int i = tid; i < NB * NPTS / 4; i += 256) {
        const float4 a = ps[i], c = ts[i];
        const float d0 = a.x - c.x, d1 = a.y - c.y;
        const float d2 = a.z - c.z, d3 = a.w - c.w;
        szs += fmaf(d0, d0, fmaf(d1, d1, fmaf(d2, d2, d3 * d3)));
    }
    szs = block_sum(szs, red);

    if (tid == 0) {
        const float cd     = acc2[0] / (float)NB;
        const float dens   = acc2[1] / (float)NB;
        const float kl     = -0.5f * kls / (float)(NB * NLAT);
        const float sizing = szs / (float)(NB * NPTS);
        out[0] = cd + 0.001f * kl + 0.1f * dens + 0.05f * sizing;
    }
}

// ---------------------------------------------------------------------------
extern "C" void kernel_launch(void* const* d_in, const int* in_sizes, int n_in,
                              void* d_out, int out_size, void* d_ws, size_t ws_size,
                              hipStream_t stream)
{
    const float* pred_pos    = (const float*)d_in[0];
    const float* pred_sizing = (const float*)d_in[1];
    const float* targ_pos    = (const float*)d_in[2];
    const float* targ_sizing = (const float*)d_in[3];
    const float* mu          = (const float*)d_in[4];
    const float* logvar      = (const float*)d_in[5];

    unsigned int* mins = (unsigned int*)d_ws;     // 3*NB*NPTS u32 = 192 KiB

    hipMemsetAsync(mins, 0xFF, (size_t)3 * NB * NPTS * sizeof(unsigned int),
                   stream);
    k_min_dist<<<dim3(NBLK), dim3(256), 0, stream>>>(pred_pos, targ_pos, mins);
    k_final<<<dim3(1), dim3(256), 0, stream>>>(
        mins, pred_sizing, targ_sizing, mu, logvar, (float*)d_out);
}